// Round 14
// baseline (3004.664 us; speedup 1.0000x reference)
//
#include <hip/hip_runtime.h>
#include <math.h>

#define N_LAYERS 24
#define D_MODEL 768
#define D_INNER 1536
#define D_STATE 16
#define DT_RANK 48
#define D_CONV 4
#define VOCAB 50280
#define ENC_DIM 256
#define SEQ 512
#define BATCH 2
#define NTOK (SEQ*BATCH)
#define XZ_DIM (2*D_INNER)
#define PROJ_DIM (DT_RANK + 2*D_STATE)  // 80
#define DTW_PAD 64                       // dt_proj K padded 48 -> 64
#define IN_SPLIT 2                       // in_proj split-K (K=384 each)
#define XP_SPLIT 8                       // x_proj split-K (K=192 each)
#define OP_SPLIT 4                       // out_proj split-K (K=384 each)

typedef __attribute__((ext_vector_type(8))) short bf16x8;
typedef __attribute__((ext_vector_type(4))) float f32x4;

__device__ __forceinline__ float sigmoidf_(float x) { return 1.f / (1.f + __expf(-x)); }
__device__ __forceinline__ float softplusf_(float x) {
    return fmaxf(x, 0.f) + log1pf(__expf(-fabsf(x)));
}
__device__ __forceinline__ short f2bf(float f) {
    unsigned u = __float_as_uint(f);
    unsigned r = (u + 0x7FFFu + ((u >> 16) & 1u)) >> 16;
    return (short)r;
}
__device__ __forceinline__ float bf2f(short s) {
    return __uint_as_float(((unsigned)(unsigned short)s) << 16);
}
__device__ __forceinline__ void load_lds16(const void* g, void* l) {
    __builtin_amdgcn_global_load_lds((const __attribute__((address_space(1))) void*)g,
                                     (__attribute__((address_space(3))) void*)l, 16, 0, 0);
}
template<int V> __device__ __forceinline__ void vwait() {
    if constexpr (V == 0)       asm volatile("s_waitcnt vmcnt(0)" ::: "memory");
    else if constexpr (V == 3)  asm volatile("s_waitcnt vmcnt(3)" ::: "memory");
    else if constexpr (V == 4)  asm volatile("s_waitcnt vmcnt(4)" ::: "memory");
    else if constexpr (V == 6)  asm volatile("s_waitcnt vmcnt(6)" ::: "memory");
    else if constexpr (V == 8)  asm volatile("s_waitcnt vmcnt(8)" ::: "memory");
    else if constexpr (V == 12) asm volatile("s_waitcnt vmcnt(12)" ::: "memory");
    else                        asm volatile("s_waitcnt vmcnt(0)" ::: "memory");
}

// ---------------------------------------------------------------------------
__global__ __launch_bounds__(256) void cvt_k(const float* __restrict__ s,
                                             short* __restrict__ d, int n) {
    int stride = gridDim.x * 256 * 4;
    for (int i = (blockIdx.x * 256 + threadIdx.x) * 4; i + 3 < n; i += stride) {
        float4 f = *(const float4*)(s + i);
        short4 o; o.x = f2bf(f.x); o.y = f2bf(f.y); o.z = f2bf(f.z); o.w = f2bf(f.w);
        *(short4*)(d + i) = o;
    }
}

// dt_proj weights: [L][1536][48] fp32 -> [L][1536][64] bf16 zero-padded
__global__ __launch_bounds__(256) void pad_dtw_k(const float* __restrict__ src,
                                                 short* __restrict__ dst) {
    int i = blockIdx.x * 256 + threadIdx.x;
    if (i >= N_LAYERS * D_INNER * DTW_PAD) return;
    int k = i & (DTW_PAD - 1);
    int rest = i >> 6;
    dst[i] = (k < DT_RANK) ? f2bf(src[(size_t)rest * DT_RANK + k]) : (short)0;
}

// ---------------------------------------------------------------------------
__global__ __launch_bounds__(256) void transpose_x_k(const float* __restrict__ x,
                                                     float* __restrict__ xt) {
    int i = blockIdx.x * 256 + threadIdx.x;
    if (i >= SEQ * BATCH * ENC_DIM) return;
    int e = i % ENC_DIM;
    int b = (i / ENC_DIM) % BATCH;
    int l = i / (ENC_DIM * BATCH);
    xt[((size_t)(b * SEQ + l)) * ENC_DIM + e] = x[i];
}
__global__ __launch_bounds__(256) void transpose_x_bf_k(const float* __restrict__ x,
                                                        short* __restrict__ xt) {
    int i = blockIdx.x * 256 + threadIdx.x;
    if (i >= SEQ * BATCH * ENC_DIM) return;
    int e = i % ENC_DIM;
    int b = (i / ENC_DIM) % BATCH;
    int l = i / (ENC_DIM * BATCH);
    xt[((size_t)(b * SEQ + l)) * ENC_DIM + e] = f2bf(x[i]);
}

// ---------------------------------------------------------------------------
__device__ __forceinline__ float rms_scale(const float* r, int tid) {
    float s = 0.f;
    for (int i = tid; i < D_MODEL; i += 256) { float v = r[i]; s += v * v; }
    for (int o = 32; o > 0; o >>= 1) s += __shfl_down(s, o);
    __shared__ float wsum[4];
    if ((tid & 63) == 0) wsum[tid >> 6] = s;
    __syncthreads();
    float tot = wsum[0] + wsum[1] + wsum[2] + wsum[3];
    return rsqrtf(tot / (float)D_MODEL + 1e-5f);
}
__global__ __launch_bounds__(256) void rmsnorm_k(const float* __restrict__ in,
                                                 const float* __restrict__ w,
                                                 float* __restrict__ out) {
    int row = blockIdx.x;
    const float* r = in + (size_t)row * D_MODEL;
    float sc = rms_scale(r, threadIdx.x);
    for (int i = threadIdx.x; i < D_MODEL; i += 256)
        out[(size_t)row * D_MODEL + i] = r[i] * sc * w[i];
}
__global__ __launch_bounds__(256) void rmsnorm_bf_k(const float* __restrict__ in,
                                                    const float* __restrict__ w,
                                                    short* __restrict__ out) {
    int row = blockIdx.x;
    const float* r = in + (size_t)row * D_MODEL;
    float sc = rms_scale(r, threadIdx.x);
    for (int i = threadIdx.x; i < D_MODEL; i += 256)
        out[(size_t)row * D_MODEL + i] = f2bf(r[i] * sc * w[i]);
}

// ---------------------------------------------------------------------------
// bf16 MFMA NT GEMM, depth-DEPTH pipeline (DEPTH+1 LDS buffers), counted
// vmcnt + raw s_barrier, bijective-XCD-swizzled. BK=32. Split-K via
// blockIdx.z. BM in {64,128}. 256 threads.
// MODE 0: store fp32; 1: +bias; 2: softplus fp32; 3: C+=acc; 4: dual;
// 5: split-K fp32 partial; 6: softplus->bf16; 7: split-K bf16 partial.
template<int MODE, int BM, int DEPTH>
__global__ __launch_bounds__(256)
void gemm_p2(const short* __restrict__ A, const short* __restrict__ B,
             const float* __restrict__ bias, float* __restrict__ C,
             short* __restrict__ Cb,
             int M, int N, int K, int ldaE, int ldbE, int ldc, int ldcb)
{
    constexpr int NBUF = DEPTH + 1;
    constexpr int MI = BM / 32;
    constexpr int AELEM = 4 * BM;
    constexpr int BELEM = 4 * 128;
    constexpr int LA = AELEM / 256;
    constexpr int LB = BELEM / 256;
    constexpr int L = LA + LB;
    __shared__ short lA[NBUF][AELEM * 8];
    __shared__ short lB[NBUF][BELEM * 8];

    const int nx = gridDim.x;
    int lin = blockIdx.y * nx + blockIdx.x;
    const int nwg = nx * gridDim.y;
    {
        const int q = nwg >> 3, r = nwg & 7;
        const int xcd = lin & 7, win = lin >> 3;
        lin = (xcd < r ? xcd * (q + 1) : r * (q + 1) + (xcd - r) * q) + win;
    }
    const int bm = (lin % nx) * BM;
    const int bn = (lin / nx) * 128;
    const int koff = blockIdx.z * K;

    const int t = threadIdx.x;
    const int wave = t >> 6;
    const int wm = (wave >> 1) * (BM / 2), wn = (wave & 1) * 64;
    const int l15 = t & 15, l4 = (t & 63) >> 4;

    f32x4 acc[MI][4] = {};
    const int nkt = K / 32;

    auto stage = [&](int buf, int kt) {
        const int k0 = koff + kt * 32;
        #pragma unroll
        for (int u = 0; u < LA; ++u) {
            const int idx = t + u * 256;
            const int kg = idx / BM;
            const int row = idx % BM;
            load_lds16(A + (size_t)(bm + row) * ldaE + k0 + kg * 8,
                       &lA[buf][(wave * 64 + u * 256) * 8]);
        }
        #pragma unroll
        for (int u = 0; u < LB; ++u) {
            const int idx = t + u * 256;
            const int kg = idx >> 7;
            const int row = idx & 127;
            int brow = bn + row; if (brow >= N) brow = 0;
            load_lds16(B + (size_t)brow * ldbE + k0 + kg * 8,
                       &lB[buf][(wave * 64 + u * 256) * 8]);
        }
    };

    #pragma unroll
    for (int p = 0; p < DEPTH; ++p)
        if (p < nkt) stage(p, p);

    for (int kt = 0; kt < nkt; ++kt) {
        const int rem = nkt - 1 - kt;
        const int ahead = rem < (DEPTH - 1) ? rem : (DEPTH - 1);
        if (ahead == 2)      vwait<2 * L>();
        else if (ahead == 1) vwait<L>();
        else                 vwait<0>();
        __builtin_amdgcn_s_barrier();
        __builtin_amdgcn_sched_barrier(0);
        if (kt + DEPTH < nkt) stage((kt + DEPTH) % NBUF, kt + DEPTH);
        const int cbuf = kt % NBUF;
        const short* bA = lA[cbuf];
        const short* bB = lB[cbuf];
        bf16x8 af[MI], bfr[4];
        #pragma unroll
        for (int i = 0; i < MI; ++i)
            af[i] = *(const bf16x8*)&bA[(l4 * BM + wm + i * 16 + l15) * 8];
        #pragma unroll
        for (int j = 0; j < 4; ++j)
            bfr[j] = *(const bf16x8*)&bB[(l4 * 128 + wn + j * 16 + l15) * 8];
        #pragma unroll
        for (int i = 0; i < MI; ++i)
            #pragma unroll
            for (int j = 0; j < 4; ++j)
                acc[i][j] = __builtin_amdgcn_mfma_f32_16x16x32_bf16(
                    af[i], bfr[j], acc[i][j], 0, 0, 0);
    }

    float* Cp = (MODE == 5) ? C + (size_t)blockIdx.z * M * ldc : C;
    short* Cbp = (MODE == 7) ? Cb + (size_t)blockIdx.z * M * ldcb : Cb;
    #pragma unroll
    for (int i = 0; i < MI; ++i) {
        #pragma unroll
        for (int r = 0; r < 4; ++r) {
            const int row = bm + wm + i * 16 + l4 * 4 + r;
            #pragma unroll
            for (int j = 0; j < 4; ++j) {
                const int col = bn + wn + j * 16 + l15;
                if (col < N) {
                    float v = acc[i][j][r];
                    if (MODE == 6) {
                        Cb[(size_t)row * ldcb + col] = f2bf(softplusf_(v + bias[col]));
                    } else if (MODE == 7) {
                        Cbp[(size_t)row * ldcb + col] = f2bf(v);
                    } else {
                        if (MODE == 1) v += bias[col];
                        if (MODE == 2) v = softplusf_(v + bias[col]);
                        if (MODE == 3) v += C[(size_t)row * ldc + col];
                        Cp[(size_t)row * ldc + col] = v;
                        if (MODE == 4) Cb[(size_t)row * ldcb + col] = f2bf(v);
                    }
                }
            }
        }
    }
}

// ---------------------------------------------------------------------------
// Wide logits GEMM: BM=128 x BN=256, 512 threads = 8 waves (2M x 4N of
// 64x64), BK=32, NBUF=3, depth-2 counted-vmcnt pipeline. 72KB LDS ->
// 2 blocks/CU = 16 waves/CU (~50% occupancy). Plain fp32 store, N guarded.
__global__ __launch_bounds__(512)
void gemm_wide(const short* __restrict__ A, const short* __restrict__ B,
               float* __restrict__ C, int M, int N, int K,
               int ldaE, int ldbE, int ldc)
{
    constexpr int NBUF = 3;
    __shared__ short lA[NBUF][4 * 128 * 8];   // 8 KB / buf
    __shared__ short lB[NBUF][4 * 256 * 8];   // 16 KB / buf

    const int nx = gridDim.x;                 // M tiles (8)
    int lin = blockIdx.y * nx + blockIdx.x;
    const int nwg = nx * gridDim.y;
    {
        const int q = nwg >> 3, r = nwg & 7;
        const int xcd = lin & 7, win = lin >> 3;
        lin = (xcd < r ? xcd * (q + 1) : r * (q + 1) + (xcd - r) * q) + win;
    }
    const int bm = (lin % nx) * 128;
    const int bn = (lin / nx) * 256;

    const int t = threadIdx.x;
    const int wave = t >> 6;
    const int wm = (wave >> 2) * 64;          // 2 M halves
    const int wn = (wave & 3) * 64;           // 4 N quarters
    const int l15 = t & 15, l4 = (t & 63) >> 4;

    f32x4 acc[4][4] = {};
    const int nkt = K / 32;

    auto stage = [&](int buf, int kt) {
        const int k0 = kt * 32;
        {   // A: 512 16B units, 1 load/thread
            const int kg = t >> 7, row = t & 127;
            load_lds16(A + (size_t)(bm + row) * ldaE + k0 + kg * 8,
                       &lA[buf][(wave * 64) * 8]);
        }
        #pragma unroll
        for (int u = 0; u < 2; ++u) {         // B: 1024 units, 2 loads/thread
            const int idx = t + u * 512;
            const int kg = idx >> 8, row = idx & 255;
            int brow = bn + row; if (brow >= N) brow = 0;
            load_lds16(B + (size_t)brow * ldbE + k0 + kg * 8,
                       &lB[buf][(wave * 64 + u * 512) * 8]);
        }
    };

    stage(0, 0);
    if (nkt > 1) stage(1, 1);
    for (int kt = 0; kt < nkt; ++kt) {
        const int rem = nkt - 1 - kt;
        if (rem >= 2)      vwait<6>();        // 2 stages x 3 loads in flight
        else if (rem == 1) vwait<3>();
        else               vwait<0>();
        __builtin_amdgcn_s_barrier();
        __builtin_amdgcn_sched_barrier(0);
        if (kt + 2 < nkt) stage((kt + 2) % NBUF, kt + 2);
        const int cbuf = kt % NBUF;
        const short* bA = lA[cbuf];
        const short* bB = lB[cbuf];
        bf16x8 af[4], bfr[4];
        #pragma unroll
        for (int i = 0; i < 4; ++i)
            af[i] = *(const bf16x8*)&bA[(l4 * 128 + wm + i * 16 + l15) * 8];
        #pragma unroll
        for (int j = 0; j < 4; ++j)
            bfr[j] = *(const bf16x8*)&bB[(l4 * 256 + wn + j * 16 + l15) * 8];
        #pragma unroll
        for (int i = 0; i < 4; ++i)
            #pragma unroll
            for (int j = 0; j < 4; ++j)
                acc[i][j] = __builtin_amdgcn_mfma_f32_16x16x32_bf16(
                    af[i], bfr[j], acc[i][j], 0, 0, 0);
    }

    #pragma unroll
    for (int i = 0; i < 4; ++i) {
        #pragma unroll
        for (int r = 0; r < 4; ++r) {
            const int row = bm + wm + i * 16 + l4 * 4 + r;
            #pragma unroll
            for (int j = 0; j < 4; ++j) {
                const int col = bn + wn + j * 16 + l15;
                if (col < N) C[(size_t)row * ldc + col] = acc[i][j][r];
            }
        }
    }
}

// ---------------------------------------------------------------------------
// in_proj reduce (2 bf16 partials) fused with depthwise conv + SiLU.
__global__ __launch_bounds__(256) void reduce_conv_k(const short* __restrict__ part,
                                                     const float* __restrict__ cw,
                                                     const float* __restrict__ cb,
                                                     short* __restrict__ xcb,
                                                     short* __restrict__ zb) {
    int idx = blockIdx.x * 256 + threadIdx.x;
    if (idx >= NTOK * XZ_DIM) return;
    int d3 = idx % XZ_DIM;
    int m  = idx / XZ_DIM;
    if (d3 < D_INNER) {
        int l = m % SEQ;
        float acc = cb[d3];
        #pragma unroll
        for (int j = 0; j < D_CONV; ++j) {
            int ll = l - (D_CONV - 1) + j;
            if (ll >= 0) {
                int mm = m - (D_CONV - 1) + j;
                float v = bf2f(part[(size_t)mm * XZ_DIM + d3])
                        + bf2f(part[(size_t)(NTOK + mm) * XZ_DIM + d3]);
                acc = fmaf(cw[d3 * D_CONV + j], v, acc);
            }
        }
        float v = acc * sigmoidf_(acc);
        xcb[(size_t)m * D_INNER + d3] = f2bf(v);
    } else {
        int d = d3 - D_INNER;
        float z = bf2f(part[(size_t)m * XZ_DIM + d3])
                + bf2f(part[(size_t)(NTOK + m) * XZ_DIM + d3]);
        zb[(size_t)m * D_INNER + d] = f2bf(z);
    }
}

// x_proj reduce: sum 8 bf16 partials [8][NTOK][80] -> proj fp32 + proj_bf.
__global__ __launch_bounds__(256) void reduce_xp_k(const short* __restrict__ part,
                                                   float* __restrict__ proj,
                                                   short* __restrict__ projb) {
    const int n4 = NTOK * PROJ_DIM / 4;
    int i = blockIdx.x * 256 + threadIdx.x;
    if (i >= n4) return;
    float sx = 0.f, sy = 0.f, sz = 0.f, sw = 0.f;
    #pragma unroll
    for (int p = 0; p < XP_SPLIT; ++p) {
        short4 v = ((const short4*)part)[i + p * n4];
        sx += bf2f(v.x); sy += bf2f(v.y); sz += bf2f(v.z); sw += bf2f(v.w);
    }
    float4 s = make_float4(sx, sy, sz, sw);
    ((float4*)proj)[i] = s;
    short4 o; o.x = f2bf(sx); o.y = f2bf(sy); o.z = f2bf(sz); o.w = f2bf(sw);
    ((short4*)projb)[i] = o;
}

// out_proj reduce (bf16 partials) fused with next-layer RMSNorm.
__global__ __launch_bounds__(256) void reduce_rms_k(const short* __restrict__ part,
                                                    float* __restrict__ h,
                                                    const float* __restrict__ w,
                                                    short* __restrict__ hnb) {
    const int row = blockIdx.x;
    const int i = threadIdx.x;
    float4 s = make_float4(0.f, 0.f, 0.f, 0.f);
    if (i < 192) {
        s = ((const float4*)h)[row * 192 + i];
        #pragma unroll
        for (int p = 0; p < OP_SPLIT; ++p) {
            short4 v = ((const short4*)part)[((size_t)p * NTOK + row) * 192 + i];
            s.x += bf2f(v.x); s.y += bf2f(v.y); s.z += bf2f(v.z); s.w += bf2f(v.w);
        }
        ((float4*)h)[row * 192 + i] = s;
    }
    float ss = s.x * s.x + s.y * s.y + s.z * s.z + s.w * s.w;
    for (int o = 32; o > 0; o >>= 1) ss += __shfl_down(ss, o);
    __shared__ float wsum[4];
    if ((i & 63) == 0) wsum[i >> 6] = ss;
    __syncthreads();
    float tot = wsum[0] + wsum[1] + wsum[2] + wsum[3];
    float sc = rsqrtf(tot / (float)D_MODEL + 1e-5f);
    if (i < 192) {
        float4 w4 = ((const float4*)w)[i];
        short4 o4;
        o4.x = f2bf(s.x * sc * w4.x); o4.y = f2bf(s.y * sc * w4.y);
        o4.z = f2bf(s.z * sc * w4.z); o4.w = f2bf(s.w * sc * w4.w);
        ((short4*)hnb)[row * 192 + i] = o4;
    }
}

// ---------------------------------------------------------------------------
// Tier-B fallback GEMM (fp32 in, converts in staging).
template<int MODE>
__global__ __launch_bounds__(256)
void gemm_bf16(const float* __restrict__ A, const float* __restrict__ B,
               const float* __restrict__ bias, float* __restrict__ C,
               int M, int N, int K, int lda, int ldb, int ldc)
{
    __shared__ short lA[4 * 128 * 8];
    __shared__ short lB[4 * 128 * 8];
    const int bm = blockIdx.x * 128;
    const int bn = blockIdx.y * 128;
    const int t = threadIdx.x;
    const int wave = t >> 6, lane = t & 63;
    const int wm = (wave >> 1) * 64, wn = (wave & 1) * 64;
    const int l15 = lane & 15, l4 = lane >> 4;
    const int row2 = t >> 1;
    const int khalf = (t & 1) * 16;
    const int kgbase = khalf >> 3;
    f32x4 acc[4][4] = {};
    const int nkt = (K + 31) / 32;
    for (int kt = 0; kt < nkt; ++kt) {
        const int k0 = kt * 32 + khalf;
        {
            short v[16];
            const float* src = A + (size_t)(bm + row2) * lda + k0;
            if (k0 + 16 <= K) {
                #pragma unroll
                for (int j = 0; j < 16; j += 4) {
                    float4 f = *(const float4*)(src + j);
                    v[j+0]=f2bf(f.x); v[j+1]=f2bf(f.y); v[j+2]=f2bf(f.z); v[j+3]=f2bf(f.w);
                }
            } else {
                #pragma unroll
                for (int j = 0; j < 16; ++j)
                    v[j] = (k0 + j < K) ? f2bf(src[j]) : (short)0;
            }
            short* dst = &lA[(kgbase * 128 + row2) * 8];
            *(bf16x8*)dst = *(const bf16x8*)&v[0];
            *(bf16x8*)(dst + 128 * 8) = *(const bf16x8*)&v[8];
        }
        {
            short v[16];
            const int nrow = bn + row2;
            if (nrow < N) {
                const float* src = B + (size_t)nrow * ldb + k0;
                if (k0 + 16 <= K) {
                    #pragma unroll
                    for (int j = 0; j < 16; j += 4) {
                        float4 f = *(const float4*)(src + j);
                        v[j+0]=f2bf(f.x); v[j+1]=f2bf(f.y); v[j+2]=f2bf(f.z); v[j+3]=f2bf(f.w);
                    }
                } else {
                    #pragma unroll
                    for (int j = 0; j < 16; ++j)
                        v[j] = (k0 + j < K) ? f2bf(src[j]) : (short)0;
                }
            } else {
                #pragma unroll
                for (int j = 0; j < 16; ++j) v[j] = 0;
            }
            short* dst = &lB[(kgbase * 128 + row2) * 8];
            *(bf16x8*)dst = *(const bf16x8*)&v[0];
            *(bf16x8*)(dst + 128 * 8) = *(const bf16x8*)&v[8];
        }
        __syncthreads();
        bf16x8 af[4], bfr[4];
        #pragma unroll
        for (int i = 0; i < 4; ++i)
            af[i] = *(const bf16x8*)&lA[(l4 * 128 + wm + i * 16 + l15) * 8];
        #pragma unroll
        for (int j = 0; j < 4; ++j)
            bfr[j] = *(const bf16x8*)&lB[(l4 * 128 + wn + j * 16 + l15) * 8];
        #pragma unroll
        for (int i = 0; i < 4; ++i)
            #pragma unroll
            for (int j = 0; j < 4; ++j)
                acc[i][j] = __builtin_amdgcn_mfma_f32_16x16x32_bf16(
                    af[i], bfr[j], acc[i][j], 0, 0, 0);
        __syncthreads();
    }
    #pragma unroll
    for (int i = 0; i < 4; ++i) {
        #pragma unroll
        for (int r = 0; r < 4; ++r) {
            const int row = bm + wm + i * 16 + l4 * 4 + r;
            #pragma unroll
            for (int j = 0; j < 4; ++j) {
                const int col = bn + wn + j * 16 + l15;
                if (col < N) {
                    float v = acc[i][j][r];
                    if (MODE == 1) v += bias[col];
                    if (MODE == 2) v = softplusf_(v + bias[col]);
                    if (MODE == 3) v += C[(size_t)row * ldc + col];
                    C[(size_t)row * ldc + col] = v;
                }
            }
        }
    }
}

// ---------------------------------------------------------------------------
template<int DUAL>
__global__ __launch_bounds__(256) void conv_silu_k(const float* __restrict__ xz,
                                                   const float* __restrict__ cw,
                                                   const float* __restrict__ cb,
                                                   float* __restrict__ xc,
                                                   short* __restrict__ xcb) {
    int idx = blockIdx.x * 256 + threadIdx.x;
    if (idx >= NTOK * D_INNER) return;
    int d = idx % D_INNER;
    int m = idx / D_INNER;
    int l = m % SEQ;
    float acc = cb[d];
    #pragma unroll
    for (int j = 0; j < D_CONV; ++j) {
        int ll = l - (D_CONV - 1) + j;
        if (ll >= 0)
            acc = fmaf(cw[d * D_CONV + j],
                       xz[(size_t)(m - (D_CONV - 1) + j) * XZ_DIM + d], acc);
    }
    float v = acc * sigmoidf_(acc);
    xc[(size_t)m * D_INNER + d] = v;
    if (DUAL) xcb[(size_t)m * D_INNER + d] = f2bf(v);
}

// ---------------------------------------------------------------------------
// Coalesced chunked selective scan. BF=1: dt/xc/z inputs bf16, y out bf16.
#define SCAN_DW 16
#define SCAN_NC 32
#define SCAN_CL (SEQ / SCAN_NC)   // 16
template<int BF>
__global__ __launch_bounds__(512) void scan3_k(const float* __restrict__ proj,
                                               const void* __restrict__ dtp,
                                               const void* __restrict__ xcp,
                                               const void* __restrict__ zp,
                                               int zld,
                                               const float* __restrict__ A_log,
                                               const float* __restrict__ Dvec,
                                               void* __restrict__ yout) {
    __shared__ float lp[D_STATE][SCAN_NC][SCAN_DW];
    __shared__ float ls[D_STATE][SCAN_NC][SCAN_DW];
    const int nblk_d = D_INNER / SCAN_DW;        // 96
    const int b  = blockIdx.x / nblk_d;
    const int d0 = (blockIdx.x % nblk_d) * SCAN_DW;
    const int t  = threadIdx.x;
    const int dl = t & (SCAN_DW - 1);
    const int c  = t >> 4;
    const int d  = d0 + dl;

    float A[D_STATE];
    #pragma unroll
    for (int s = 0; s < D_STATE; s += 4) {
        float4 a4 = *(const float4*)&A_log[(size_t)d * D_STATE + s];
        A[s+0] = -__expf(a4.x); A[s+1] = -__expf(a4.y);
        A[s+2] = -__expf(a4.z); A[s+3] = -__expf(a4.w);
    }
    const int m0 = b * SEQ + c * SCAN_CL;

    float P[D_STATE], S[D_STATE];
    #pragma unroll
    for (int s = 0; s < D_STATE; ++s) { P[s] = 1.f; S[s] = 0.f; }
    for (int i = 0; i < SCAN_CL; ++i) {
        const int m = m0 + i;
        float dtv, xcv;
        if (BF) {
            dtv = bf2f(((const short*)dtp)[(size_t)m * D_INNER + d]);
            xcv = bf2f(((const short*)xcp)[(size_t)m * D_INNER + d]);
        } else {
            dtv = ((const float*)dtp)[(size_t)m * D_INNER + d];
            xcv = ((const float*)xcp)[(size_t)m * D_INNER + d];
        }
        float dx = dtv * xcv;
        const float* pB = proj + (size_t)m * PROJ_DIM + DT_RANK;
        float Bv[D_STATE];
        #pragma unroll
        for (int s = 0; s < D_STATE; s += 4)
            *(float4*)&Bv[s] = *(const float4*)(pB + s);
        #pragma unroll
        for (int s = 0; s < D_STATE; ++s) {
            float da = __expf(dtv * A[s]);
            S[s] = fmaf(da, S[s], dx * Bv[s]);
            P[s] *= da;
        }
    }
    #pragma unroll
    for (int s = 0; s < D_STATE; ++s) { lp[s][c][dl] = P[s]; ls[s][c][dl] = S[s]; }
    __syncthreads();

    float st[D_STATE];
    #pragma unroll
    for (int s = 0; s < D_STATE; ++s) st[s] = 0.f;
    for (int j = 0; j < c; ++j) {
        #pragma unroll
        for (int s = 0; s < D_STATE; ++s)
            st[s] = fmaf(lp[s][j][dl], st[s], ls[s][j][dl]);
    }

    const float Dvv = Dvec[d];
    for (int i = 0; i < SCAN_CL; ++i) {
        const int m = m0 + i;
        float dtv, xcv, zv;
        if (BF) {
            dtv = bf2f(((const short*)dtp)[(size_t)m * D_INNER + d]);
            xcv = bf2f(((const short*)xcp)[(size_t)m * D_INNER + d]);
            zv  = bf2f(((const short*)zp)[(size_t)m * zld + d]);
        } else {
            dtv = ((const float*)dtp)[(size_t)m * D_INNER + d];
            xcv = ((const float*)xcp)[(size_t)m * D_INNER + d];
            zv  = ((const float*)zp)[(size_t)m * zld + d];
        }
        float dx = dtv * xcv;
        const float* pB = proj + (size_t)m * PROJ_DIM + DT_RANK;
        float Bv[D_STATE], Cv[D_STATE];
        #pragma unroll
        for (int s = 0; s < D_STATE; s += 4) {
            *(float4*)&Bv[s] = *(const float4*)(pB + s);
            *(float4*)&Cv[s] = *(const float4*)(pB + D_STATE + s);
        }
        float acc = Dvv * xcv;
        #pragma unroll
        for (int s = 0; s < D_STATE; ++s) {
            float da = __expf(dtv * A[s]);
            st[s] = fmaf(da, st[s], dx * Bv[s]);
            acc = fmaf(st[s], Cv[s], acc);
        }
        float yv = acc * (zv * sigmoidf_(zv));
        if (BF) ((short*)yout)[(size_t)m * D_INNER + d] = f2bf(yv);
        else    ((float*)yout)[(size_t)m * D_INNER + d] = yv;
    }
}

// ---------------------------------------------------------------------------
extern "C" void kernel_launch(void* const* d_in, const int* in_sizes, int n_in,
                              void* d_out, int out_size, void* d_ws, size_t ws_size,
                              hipStream_t stream) {
    const float* x           = (const float*)d_in[0];
    const float* W_et        = (const float*)d_in[1];
    const float* b_et        = (const float*)d_in[2];
    const float* in_proj_w   = (const float*)d_in[3];
    const float* conv_w      = (const float*)d_in[4];
    const float* conv_b      = (const float*)d_in[5];
    const float* x_proj_w    = (const float*)d_in[6];
    const float* dt_proj_w   = (const float*)d_in[7];
    const float* dt_proj_b   = (const float*)d_in[8];
    const float* A_log       = (const float*)d_in[9];
    const float* Dv          = (const float*)d_in[10];
    const float* out_proj_w  = (const float*)d_in[11];
    const float* norm_w      = (const float*)d_in[12];
    const float* final_norm_w= (const float*)d_in[13];
    const float* embed       = (const float*)d_in[14];
    float* out = (float*)d_out;
    float* ws  = (float*)d_ws;

    // ---- tier-A layout (R11) ----
    float* h       = ws;                                    // [NTOK][768]
    float* proj    = h + (size_t)NTOK * D_MODEL;            // [NTOK][80]
    float* scratch = proj + (size_t)NTOK * PROJ_DIM;        // partials region
    short* scratch_bf = (short*)scratch;
    short* xt_bf   = (short*)(scratch + (size_t)IN_SPLIT * NTOK * XZ_DIM);
    short* hn_bf   = xt_bf   + (size_t)NTOK * ENC_DIM;
    short* xc_bf   = hn_bf   + (size_t)NTOK * D_MODEL;
    short* z_bf    = xc_bf   + (size_t)NTOK * D_INNER;
    short* dt_bf   = z_bf    + (size_t)NTOK * D_INNER;
    short* proj_bf = dt_bf   + (size_t)NTOK * D_INNER;
    short* yb_bf   = proj_bf + (size_t)NTOK * PROJ_DIM;
    short* wet_bf  = yb_bf   + (size_t)NTOK * D_INNER;
    short* inw_bf  = wet_bf  + (size_t)D_MODEL * ENC_DIM;
    short* xw_bf   = inw_bf  + (size_t)N_LAYERS * XZ_DIM * D_MODEL;
    short* dtw_bf  = xw_bf   + (size_t)N_LAYERS * PROJ_DIM * D_INNER;
    short* ow_bf   = dtw_bf  + (size_t)N_LAYERS * D_INNER * DTW_PAD;
    short* emb_bf  = ow_bf   + (size_t)N_LAYERS * D_MODEL * D_INNER;
    short* end_bf  = emb_bf  + (size_t)VOCAB * D_MODEL;
    size_t needA = (size_t)((char*)end_bf - (char*)d_ws);
    bool tierA = ws_size >= needA;

    dim3 blk(256);
    const int scan_blocks = BATCH * (D_INNER / SCAN_DW);   // 192

    if (tierA) {
        auto cvt = [&](const float* s, short* d, size_t n) {
            int nb = (int)((n / 4 + 255) / 256); if (nb > 2048) nb = 2048;
            cvt_k<<<nb, blk, 0, stream>>>(s, d, (int)n);
        };
        cvt(W_et, wet_bf, (size_t)D_MODEL * ENC_DIM);
        cvt(in_proj_w, inw_bf, (size_t)N_LAYERS * XZ_DIM * D_MODEL);
        cvt(x_proj_w, xw_bf, (size_t)N_LAYERS * PROJ_DIM * D_INNER);
        cvt(out_proj_w, ow_bf, (size_t)N_LAYERS * D_MODEL * D_INNER);
        cvt(embed, emb_bf, (size_t)VOCAB * D_MODEL);
        pad_dtw_k<<<(N_LAYERS * D_INNER * DTW_PAD + 255) / 256, blk, 0, stream>>>(
            dt_proj_w, dtw_bf);

        transpose_x_bf_k<<<(SEQ * BATCH * ENC_DIM + 255) / 256, blk, 0, stream>>>(x, xt_bf);
        gemm_p2<1, 64, 2><<<dim3(NTOK / 64, D_MODEL / 128), blk, 0, stream>>>(
            xt_bf, wet_bf, b_et, h, nullptr,
            NTOK, D_MODEL, ENC_DIM, ENC_DIM, ENC_DIM, D_MODEL, 0);
        rmsnorm_bf_k<<<NTOK, blk, 0, stream>>>(h, norm_w, hn_bf);

        for (int L = 0; L < N_LAYERS; ++L) {
            const short* in_w = inw_bf + (size_t)L * XZ_DIM * D_MODEL;
            const float* cw   = conv_w + (size_t)L * D_INNER * D_CONV;
            const float* cb   = conv_b + (size_t)L * D_INNER;
            const short* xw   = xw_bf  + (size_t)L * PROJ_DIM * D_INNER;
            const short* dtw  = dtw_bf + (size_t)L * D_INNER * DTW_PAD;
            const float* dtbp = dt_proj_b + (size_t)L * D_INNER;
            const float* Al   = A_log  + (size_t)L * D_INNER * D_STATE;
            const float* Dl   = Dv     + (size_t)L * D_INNER;
            const short* ow   = ow_bf  + (size_t)L * D_MODEL * D_INNER;
            const float* nw_next = (L == N_LAYERS - 1) ? final_norm_w
                                 : norm_w + (size_t)(L + 1) * D_MODEL;

            gemm_p2<7, 64, 3><<<dim3(NTOK / 64, XZ_DIM / 128, IN_SPLIT), blk, 0, stream>>>(
                hn_bf, in_w, nullptr, nullptr, scratch_bf,
                NTOK, XZ_DIM, D_MODEL / IN_SPLIT, D_MODEL, D_MODEL, 0, XZ_DIM);
            reduce_conv_k<<<(NTOK * XZ_DIM + 255) / 256, blk, 0, stream>>>(
                scratch_bf, cw, cb, xc_bf, z_bf);
            gemm_p2<7, 64, 3><<<dim3(NTOK / 64, 1, XP_SPLIT), blk, 0, stream>>>(
                xc_bf, xw, nullptr, nullptr, scratch_bf,
                NTOK, PROJ_DIM, D_INNER / XP_SPLIT, D_INNER, D_INNER, 0, PROJ_DIM);
            reduce_xp_k<<<(NTOK * PROJ_DIM / 4 + 255) / 256, blk, 0, stream>>>(
                scratch_bf, proj, proj_bf);
            gemm_p2<6, 64, 2><<<dim3(NTOK / 64, D_INNER / 128), blk, 0, stream>>>(
                proj_bf, dtw, dtbp, h /*dummy*/, dt_bf,
                NTOK, D_INNER, DTW_PAD, PROJ_DIM, DTW_PAD, D_INNER, D_INNER);
            scan3_k<1><<<scan_blocks, dim3(512), 0, stream>>>(
                proj, dt_bf, xc_bf, z_bf, D_INNER, Al, Dl, yb_bf);
            gemm_p2<7, 64, 3><<<dim3(NTOK / 64, D_MODEL / 128, OP_SPLIT), blk, 0, stream>>>(
                yb_bf, ow, nullptr, nullptr, scratch_bf,
                NTOK, D_MODEL, D_INNER / OP_SPLIT, D_INNER, D_INNER, 0, D_MODEL);
            reduce_rms_k<<<NTOK, blk, 0, stream>>>(scratch_bf, h, nw_next, hn_bf);
        }

        gemm_wide<<<dim3(NTOK / 128, (VOCAB + 255) / 256), dim3(512), 0, stream>>>(
            hn_bf, emb_bf, out, NTOK, VOCAB, D_MODEL, D_MODEL, D_MODEL, VOCAB);
    } else {
        // ---- tier B fallback (fp32 intermediates) ----
        float* hB   = ws;
        float* hnB  = hB   + (size_t)NTOK * D_MODEL;
        float* xzB  = hnB  + (size_t)NTOK * D_MODEL;
        float* xcB  = xzB  + (size_t)NTOK * XZ_DIM;
        float* projB= xcB  + (size_t)NTOK * D_INNER;
        float* dtB  = projB+ (size_t)NTOK * PROJ_DIM;
        float* ybB  = dtB  + (size_t)NTOK * D_INNER;

        transpose_x_k<<<(SEQ * BATCH * ENC_DIM + 255) / 256, blk, 0, stream>>>(x, ybB);
        gemm_bf16<1><<<dim3(NTOK / 128, D_MODEL / 128), blk, 0, stream>>>(
            ybB, W_et, b_et, hB, NTOK, D_MODEL, ENC_DIM, ENC_DIM, ENC_DIM, D_MODEL);
        for (int L = 0; L < N_LAYERS; ++L) {
            const float* in_w = in_proj_w  + (size_t)L * XZ_DIM * D_MODEL;
            const float* cw   = conv_w     + (size_t)L * D_INNER * D_CONV;
            const float* cb   = conv_b     + (size_t)L * D_INNER;
            const float* xw   = x_proj_w   + (size_t)L * PROJ_DIM * D_INNER;
            const float* dtw  = dt_proj_w  + (size_t)L * D_INNER * DT_RANK;
            const float* dtbp = dt_proj_b  + (size_t)L * D_INNER;
            const float* Al   = A_log      + (size_t)L * D_INNER * D_STATE;
            const float* Dl   = Dv         + (size_t)L * D_INNER;
            const float* ow   = out_proj_w + (size_t)L * D_MODEL * D_INNER;
            const float* nw   = norm_w     + (size_t)L * D_MODEL;
            rmsnorm_k<<<NTOK, blk, 0, stream>>>(hB, nw, hnB);
            gemm_bf16<0><<<dim3(NTOK / 128, XZ_DIM / 128), blk, 0, stream>>>(
                hnB, in_w, nullptr, xzB, NTOK, XZ_DIM, D_MODEL, D_MODEL, D_MODEL, XZ_DIM);
            conv_silu_k<0><<<(NTOK * D_INNER + 255) / 256, blk, 0, stream>>>(
                xzB, cw, cb, xcB, nullptr);
            gemm_bf16<0><<<dim3(NTOK / 128, 1), blk, 0, stream>>>(
                xcB, xw, nullptr, projB, NTOK, PROJ_DIM, D_INNER, D_INNER, D_INNER, PROJ_DIM);
            gemm_bf16<2><<<dim3(NTOK / 128, D_INNER / 128), blk, 0, stream>>>(
                projB, dtw, dtbp, dtB, NTOK, D_INNER, DT_RANK, PROJ_DIM, DT_RANK, D_INNER);
            scan3_k<0><<<scan_blocks, dim3(512), 0, stream>>>(
                projB, dtB, xcB, xzB + D_INNER, XZ_DIM, Al, Dl, ybB);
            gemm_bf16<3><<<dim3(NTOK / 128, D_MODEL / 128), blk, 0, stream>>>(
                ybB, ow, nullptr, hB, NTOK, D_MODEL, D_INNER, D_INNER, D_INNER, D_MODEL);
        }
        rmsnorm_k<<<NTOK, blk, 0, stream>>>(hB, final_norm_w, hnB);
        gemm_bf16<0><<<dim3(NTOK / 128, (VOCAB + 127) / 128), blk, 0, stream>>>(
            hnB, embed, nullptr, out, NTOK, VOCAB, D_MODEL, D_MODEL, D_MODEL, VOCAB);
    }
}

// Round 15
// 2903.467 us; speedup vs baseline: 1.0349x; 1.0349x over previous
//
#include <hip/hip_runtime.h>
#include <math.h>

#define N_LAYERS 24
#define D_MODEL 768
#define D_INNER 1536
#define D_STATE 16
#define DT_RANK 48
#define D_CONV 4
#define VOCAB 50280
#define ENC_DIM 256
#define SEQ 512
#define BATCH 2
#define NTOK (SEQ*BATCH)
#define XZ_DIM (2*D_INNER)
#define PROJ_DIM (DT_RANK + 2*D_STATE)  // 80
#define DTW_PAD 64                       // dt_proj K padded 48 -> 64
#define IN_SPLIT 2                       // in_proj split-K (K=384 each)
#define XP_SPLIT 8                       // x_proj split-K (K=192 each)
#define OP_SPLIT 4                       // out_proj split-K (K=384 each)

typedef __attribute__((ext_vector_type(8))) short bf16x8;
typedef __attribute__((ext_vector_type(4))) float f32x4;

__device__ __forceinline__ float sigmoidf_(float x) { return 1.f / (1.f + __expf(-x)); }
__device__ __forceinline__ float softplusf_(float x) {
    return fmaxf(x, 0.f) + log1pf(__expf(-fabsf(x)));
}
__device__ __forceinline__ short f2bf(float f) {
    unsigned u = __float_as_uint(f);
    unsigned r = (u + 0x7FFFu + ((u >> 16) & 1u)) >> 16;
    return (short)r;
}
__device__ __forceinline__ float bf2f(short s) {
    return __uint_as_float(((unsigned)(unsigned short)s) << 16);
}
__device__ __forceinline__ void load_lds16(const void* g, void* l) {
    __builtin_amdgcn_global_load_lds((const __attribute__((address_space(1))) void*)g,
                                     (__attribute__((address_space(3))) void*)l, 16, 0, 0);
}
template<int V> __device__ __forceinline__ void vwait() {
    if constexpr (V == 0)       asm volatile("s_waitcnt vmcnt(0)" ::: "memory");
    else if constexpr (V == 3)  asm volatile("s_waitcnt vmcnt(3)" ::: "memory");
    else if constexpr (V == 4)  asm volatile("s_waitcnt vmcnt(4)" ::: "memory");
    else if constexpr (V == 6)  asm volatile("s_waitcnt vmcnt(6)" ::: "memory");
    else if constexpr (V == 8)  asm volatile("s_waitcnt vmcnt(8)" ::: "memory");
    else if constexpr (V == 12) asm volatile("s_waitcnt vmcnt(12)" ::: "memory");
    else                        asm volatile("s_waitcnt vmcnt(0)" ::: "memory");
}

// ---------------------------------------------------------------------------
__global__ __launch_bounds__(256) void cvt_k(const float* __restrict__ s,
                                             short* __restrict__ d, int n) {
    int stride = gridDim.x * 256 * 4;
    for (int i = (blockIdx.x * 256 + threadIdx.x) * 4; i + 3 < n; i += stride) {
        float4 f = *(const float4*)(s + i);
        short4 o; o.x = f2bf(f.x); o.y = f2bf(f.y); o.z = f2bf(f.z); o.w = f2bf(f.w);
        *(short4*)(d + i) = o;
    }
}

// dt_proj weights: [L][1536][48] fp32 -> [L][1536][64] bf16 zero-padded
__global__ __launch_bounds__(256) void pad_dtw_k(const float* __restrict__ src,
                                                 short* __restrict__ dst) {
    int i = blockIdx.x * 256 + threadIdx.x;
    if (i >= N_LAYERS * D_INNER * DTW_PAD) return;
    int k = i & (DTW_PAD - 1);
    int rest = i >> 6;
    dst[i] = (k < DT_RANK) ? f2bf(src[(size_t)rest * DT_RANK + k]) : (short)0;
}

// ---------------------------------------------------------------------------
__global__ __launch_bounds__(256) void transpose_x_k(const float* __restrict__ x,
                                                     float* __restrict__ xt) {
    int i = blockIdx.x * 256 + threadIdx.x;
    if (i >= SEQ * BATCH * ENC_DIM) return;
    int e = i % ENC_DIM;
    int b = (i / ENC_DIM) % BATCH;
    int l = i / (ENC_DIM * BATCH);
    xt[((size_t)(b * SEQ + l)) * ENC_DIM + e] = x[i];
}
__global__ __launch_bounds__(256) void transpose_x_bf_k(const float* __restrict__ x,
                                                        short* __restrict__ xt) {
    int i = blockIdx.x * 256 + threadIdx.x;
    if (i >= SEQ * BATCH * ENC_DIM) return;
    int e = i % ENC_DIM;
    int b = (i / ENC_DIM) % BATCH;
    int l = i / (ENC_DIM * BATCH);
    xt[((size_t)(b * SEQ + l)) * ENC_DIM + e] = f2bf(x[i]);
}

// ---------------------------------------------------------------------------
__device__ __forceinline__ float rms_scale(const float* r, int tid) {
    float s = 0.f;
    for (int i = tid; i < D_MODEL; i += 256) { float v = r[i]; s += v * v; }
    for (int o = 32; o > 0; o >>= 1) s += __shfl_down(s, o);
    __shared__ float wsum[4];
    if ((tid & 63) == 0) wsum[tid >> 6] = s;
    __syncthreads();
    float tot = wsum[0] + wsum[1] + wsum[2] + wsum[3];
    return rsqrtf(tot / (float)D_MODEL + 1e-5f);
}
__global__ __launch_bounds__(256) void rmsnorm_k(const float* __restrict__ in,
                                                 const float* __restrict__ w,
                                                 float* __restrict__ out) {
    int row = blockIdx.x;
    const float* r = in + (size_t)row * D_MODEL;
    float sc = rms_scale(r, threadIdx.x);
    for (int i = threadIdx.x; i < D_MODEL; i += 256)
        out[(size_t)row * D_MODEL + i] = r[i] * sc * w[i];
}
__global__ __launch_bounds__(256) void rmsnorm_bf_k(const float* __restrict__ in,
                                                    const float* __restrict__ w,
                                                    short* __restrict__ out) {
    int row = blockIdx.x;
    const float* r = in + (size_t)row * D_MODEL;
    float sc = rms_scale(r, threadIdx.x);
    for (int i = threadIdx.x; i < D_MODEL; i += 256)
        out[(size_t)row * D_MODEL + i] = f2bf(r[i] * sc * w[i]);
}

// ---------------------------------------------------------------------------
// bf16 MFMA NT GEMM, depth-DEPTH pipeline (DEPTH+1 LDS buffers), counted
// vmcnt + raw s_barrier, bijective-XCD-swizzled. BK=32. Split-K via
// blockIdx.z. BM in {64,128}. 256 threads.
// MODE 0: nontemporal fp32 store (logits); 1: +bias; 2: softplus fp32;
// 3: C+=acc; 4: dual; 5: split-K fp32 partial; 6: softplus->bf16;
// 7: split-K bf16 partial.
template<int MODE, int BM, int DEPTH>
__global__ __launch_bounds__(256)
void gemm_p2(const short* __restrict__ A, const short* __restrict__ B,
             const float* __restrict__ bias, float* __restrict__ C,
             short* __restrict__ Cb,
             int M, int N, int K, int ldaE, int ldbE, int ldc, int ldcb)
{
    constexpr int NBUF = DEPTH + 1;
    constexpr int MI = BM / 32;
    constexpr int AELEM = 4 * BM;
    constexpr int BELEM = 4 * 128;
    constexpr int LA = AELEM / 256;
    constexpr int LB = BELEM / 256;
    constexpr int L = LA + LB;
    __shared__ short lA[NBUF][AELEM * 8];
    __shared__ short lB[NBUF][BELEM * 8];

    const int nx = gridDim.x;
    int lin = blockIdx.y * nx + blockIdx.x;
    const int nwg = nx * gridDim.y;
    {
        const int q = nwg >> 3, r = nwg & 7;
        const int xcd = lin & 7, win = lin >> 3;
        lin = (xcd < r ? xcd * (q + 1) : r * (q + 1) + (xcd - r) * q) + win;
    }
    const int bm = (lin % nx) * BM;
    const int bn = (lin / nx) * 128;
    const int koff = blockIdx.z * K;

    const int t = threadIdx.x;
    const int wave = t >> 6;
    const int wm = (wave >> 1) * (BM / 2), wn = (wave & 1) * 64;
    const int l15 = t & 15, l4 = (t & 63) >> 4;

    f32x4 acc[MI][4] = {};
    const int nkt = K / 32;

    auto stage = [&](int buf, int kt) {
        const int k0 = koff + kt * 32;
        #pragma unroll
        for (int u = 0; u < LA; ++u) {
            const int idx = t + u * 256;
            const int kg = idx / BM;
            const int row = idx % BM;
            load_lds16(A + (size_t)(bm + row) * ldaE + k0 + kg * 8,
                       &lA[buf][(wave * 64 + u * 256) * 8]);
        }
        #pragma unroll
        for (int u = 0; u < LB; ++u) {
            const int idx = t + u * 256;
            const int kg = idx >> 7;
            const int row = idx & 127;
            int brow = bn + row; if (brow >= N) brow = 0;
            load_lds16(B + (size_t)brow * ldbE + k0 + kg * 8,
                       &lB[buf][(wave * 64 + u * 256) * 8]);
        }
    };

    #pragma unroll
    for (int p = 0; p < DEPTH; ++p)
        if (p < nkt) stage(p, p);

    for (int kt = 0; kt < nkt; ++kt) {
        const int rem = nkt - 1 - kt;
        const int ahead = rem < (DEPTH - 1) ? rem : (DEPTH - 1);
        if (ahead == 2)      vwait<2 * L>();
        else if (ahead == 1) vwait<L>();
        else                 vwait<0>();
        __builtin_amdgcn_s_barrier();
        __builtin_amdgcn_sched_barrier(0);
        if (kt + DEPTH < nkt) stage((kt + DEPTH) % NBUF, kt + DEPTH);
        const int cbuf = kt % NBUF;
        const short* bA = lA[cbuf];
        const short* bB = lB[cbuf];
        bf16x8 af[MI], bfr[4];
        #pragma unroll
        for (int i = 0; i < MI; ++i)
            af[i] = *(const bf16x8*)&bA[(l4 * BM + wm + i * 16 + l15) * 8];
        #pragma unroll
        for (int j = 0; j < 4; ++j)
            bfr[j] = *(const bf16x8*)&bB[(l4 * 128 + wn + j * 16 + l15) * 8];
        #pragma unroll
        for (int i = 0; i < MI; ++i)
            #pragma unroll
            for (int j = 0; j < 4; ++j)
                acc[i][j] = __builtin_amdgcn_mfma_f32_16x16x32_bf16(
                    af[i], bfr[j], acc[i][j], 0, 0, 0);
    }

    float* Cp = (MODE == 5) ? C + (size_t)blockIdx.z * M * ldc : C;
    short* Cbp = (MODE == 7) ? Cb + (size_t)blockIdx.z * M * ldcb : Cb;
    #pragma unroll
    for (int i = 0; i < MI; ++i) {
        #pragma unroll
        for (int r = 0; r < 4; ++r) {
            const int row = bm + wm + i * 16 + l4 * 4 + r;
            #pragma unroll
            for (int j = 0; j < 4; ++j) {
                const int col = bn + wn + j * 16 + l15;
                if (col < N) {
                    float v = acc[i][j][r];
                    if (MODE == 6) {
                        Cb[(size_t)row * ldcb + col] = f2bf(softplusf_(v + bias[col]));
                    } else if (MODE == 7) {
                        Cbp[(size_t)row * ldcb + col] = f2bf(v);
                    } else if (MODE == 0) {
                        __builtin_nontemporal_store(v, &Cp[(size_t)row * ldc + col]);
                    } else {
                        if (MODE == 1) v += bias[col];
                        if (MODE == 2) v = softplusf_(v + bias[col]);
                        if (MODE == 3) v += C[(size_t)row * ldc + col];
                        Cp[(size_t)row * ldc + col] = v;
                        if (MODE == 4) Cb[(size_t)row * ldcb + col] = f2bf(v);
                    }
                }
            }
        }
    }
}

// ---------------------------------------------------------------------------
// in_proj reduce (2 bf16 partials) fused with depthwise conv + SiLU.
// Vectorized: each thread handles 8 consecutive channels (bf16x8 loads,
// 16B/lane). All 8 lanes share the same token m (XZ_DIM % 8 == 0).
__global__ __launch_bounds__(256) void reduce_conv_k(const short* __restrict__ part,
                                                     const float* __restrict__ cw,
                                                     const float* __restrict__ cb,
                                                     short* __restrict__ xcb,
                                                     short* __restrict__ zb) {
    const int nv = NTOK * XZ_DIM / 8;
    int v = blockIdx.x * 256 + threadIdx.x;
    if (v >= nv) return;
    const int vpr = XZ_DIM / 8;              // 384 vectors per token row
    const int m  = v / vpr;
    const int d8 = (v - m * vpr) * 8;        // start channel in [0, XZ_DIM)
    if (d8 < D_INNER) {
        const int l = m % SEQ;
        float acc[8];
        #pragma unroll
        for (int e = 0; e < 8; e += 4) {
            float4 c4a = *(const float4*)&cb[d8 + e];
            acc[e+0] = c4a.x; acc[e+1] = c4a.y; acc[e+2] = c4a.z; acc[e+3] = c4a.w;
        }
        float w[8][D_CONV];
        #pragma unroll
        for (int e = 0; e < 8; ++e) {
            float4 w4 = *(const float4*)&cw[(d8 + e) * D_CONV];
            w[e][0] = w4.x; w[e][1] = w4.y; w[e][2] = w4.z; w[e][3] = w4.w;
        }
        #pragma unroll
        for (int j = 0; j < D_CONV; ++j) {
            int ll = l - (D_CONV - 1) + j;
            if (ll >= 0) {
                const int mm = m - (D_CONV - 1) + j;
                bf16x8 p0 = *(const bf16x8*)&part[(size_t)mm * XZ_DIM + d8];
                bf16x8 p1 = *(const bf16x8*)&part[(size_t)(NTOK + mm) * XZ_DIM + d8];
                #pragma unroll
                for (int e = 0; e < 8; ++e)
                    acc[e] = fmaf(w[e][j], bf2f(p0[e]) + bf2f(p1[e]), acc[e]);
            }
        }
        short o[8];
        #pragma unroll
        for (int e = 0; e < 8; ++e) {
            float vv = acc[e] * sigmoidf_(acc[e]);
            o[e] = f2bf(vv);
        }
        *(bf16x8*)&xcb[(size_t)m * D_INNER + d8] = *(const bf16x8*)o;
    } else {
        const int d = d8 - D_INNER;
        bf16x8 p0 = *(const bf16x8*)&part[(size_t)m * XZ_DIM + d8];
        bf16x8 p1 = *(const bf16x8*)&part[(size_t)(NTOK + m) * XZ_DIM + d8];
        short o[8];
        #pragma unroll
        for (int e = 0; e < 8; ++e) o[e] = f2bf(bf2f(p0[e]) + bf2f(p1[e]));
        *(bf16x8*)&zb[(size_t)m * D_INNER + d] = *(const bf16x8*)o;
    }
}

// x_proj reduce: sum 8 bf16 partials [8][NTOK][80] -> proj fp32 + proj_bf.
__global__ __launch_bounds__(256) void reduce_xp_k(const short* __restrict__ part,
                                                   float* __restrict__ proj,
                                                   short* __restrict__ projb) {
    const int n4 = NTOK * PROJ_DIM / 4;
    int i = blockIdx.x * 256 + threadIdx.x;
    if (i >= n4) return;
    float sx = 0.f, sy = 0.f, sz = 0.f, sw = 0.f;
    #pragma unroll
    for (int p = 0; p < XP_SPLIT; ++p) {
        short4 v = ((const short4*)part)[i + p * n4];
        sx += bf2f(v.x); sy += bf2f(v.y); sz += bf2f(v.z); sw += bf2f(v.w);
    }
    float4 s = make_float4(sx, sy, sz, sw);
    ((float4*)proj)[i] = s;
    short4 o; o.x = f2bf(sx); o.y = f2bf(sy); o.z = f2bf(sz); o.w = f2bf(sw);
    ((short4*)projb)[i] = o;
}

// out_proj reduce (bf16 partials) fused with next-layer RMSNorm.
__global__ __launch_bounds__(256) void reduce_rms_k(const short* __restrict__ part,
                                                    float* __restrict__ h,
                                                    const float* __restrict__ w,
                                                    short* __restrict__ hnb) {
    const int row = blockIdx.x;
    const int i = threadIdx.x;
    float4 s = make_float4(0.f, 0.f, 0.f, 0.f);
    if (i < 192) {
        s = ((const float4*)h)[row * 192 + i];
        #pragma unroll
        for (int p = 0; p < OP_SPLIT; ++p) {
            short4 v = ((const short4*)part)[((size_t)p * NTOK + row) * 192 + i];
            s.x += bf2f(v.x); s.y += bf2f(v.y); s.z += bf2f(v.z); s.w += bf2f(v.w);
        }
        ((float4*)h)[row * 192 + i] = s;
    }
    float ss = s.x * s.x + s.y * s.y + s.z * s.z + s.w * s.w;
    for (int o = 32; o > 0; o >>= 1) ss += __shfl_down(ss, o);
    __shared__ float wsum[4];
    if ((i & 63) == 0) wsum[i >> 6] = ss;
    __syncthreads();
    float tot = wsum[0] + wsum[1] + wsum[2] + wsum[3];
    float sc = rsqrtf(tot / (float)D_MODEL + 1e-5f);
    if (i < 192) {
        float4 w4 = ((const float4*)w)[i];
        short4 o4;
        o4.x = f2bf(s.x * sc * w4.x); o4.y = f2bf(s.y * sc * w4.y);
        o4.z = f2bf(s.z * sc * w4.z); o4.w = f2bf(s.w * sc * w4.w);
        ((short4*)hnb)[row * 192 + i] = o4;
    }
}

// ---------------------------------------------------------------------------
// Tier-B fallback GEMM (fp32 in, converts in staging).
template<int MODE>
__global__ __launch_bounds__(256)
void gemm_bf16(const float* __restrict__ A, const float* __restrict__ B,
               const float* __restrict__ bias, float* __restrict__ C,
               int M, int N, int K, int lda, int ldb, int ldc)
{
    __shared__ short lA[4 * 128 * 8];
    __shared__ short lB[4 * 128 * 8];
    const int bm = blockIdx.x * 128;
    const int bn = blockIdx.y * 128;
    const int t = threadIdx.x;
    const int wave = t >> 6, lane = t & 63;
    const int wm = (wave >> 1) * 64, wn = (wave & 1) * 64;
    const int l15 = lane & 15, l4 = lane >> 4;
    const int row2 = t >> 1;
    const int khalf = (t & 1) * 16;
    const int kgbase = khalf >> 3;
    f32x4 acc[4][4] = {};
    const int nkt = (K + 31) / 32;
    for (int kt = 0; kt < nkt; ++kt) {
        const int k0 = kt * 32 + khalf;
        {
            short v[16];
            const float* src = A + (size_t)(bm + row2) * lda + k0;
            if (k0 + 16 <= K) {
                #pragma unroll
                for (int j = 0; j < 16; j += 4) {
                    float4 f = *(const float4*)(src + j);
                    v[j+0]=f2bf(f.x); v[j+1]=f2bf(f.y); v[j+2]=f2bf(f.z); v[j+3]=f2bf(f.w);
                }
            } else {
                #pragma unroll
                for (int j = 0; j < 16; ++j)
                    v[j] = (k0 + j < K) ? f2bf(src[j]) : (short)0;
            }
            short* dst = &lA[(kgbase * 128 + row2) * 8];
            *(bf16x8*)dst = *(const bf16x8*)&v[0];
            *(bf16x8*)(dst + 128 * 8) = *(const bf16x8*)&v[8];
        }
        {
            short v[16];
            const int nrow = bn + row2;
            if (nrow < N) {
                const float* src = B + (size_t)nrow * ldb + k0;
                if (k0 + 16 <= K) {
                    #pragma unroll
                    for (int j = 0; j < 16; j += 4) {
                        float4 f = *(const float4*)(src + j);
                        v[j+0]=f2bf(f.x); v[j+1]=f2bf(f.y); v[j+2]=f2bf(f.z); v[j+3]=f2bf(f.w);
                    }
                } else {
                    #pragma unroll
                    for (int j = 0; j < 16; ++j)
                        v[j] = (k0 + j < K) ? f2bf(src[j]) : (short)0;
                }
            } else {
                #pragma unroll
                for (int j = 0; j < 16; ++j) v[j] = 0;
            }
            short* dst = &lB[(kgbase * 128 + row2) * 8];
            *(bf16x8*)dst = *(const bf16x8*)&v[0];
            *(bf16x8*)(dst + 128 * 8) = *(const bf16x8*)&v[8];
        }
        __syncthreads();
        bf16x8 af[4], bfr[4];
        #pragma unroll
        for (int i = 0; i < 4; ++i)
            af[i] = *(const bf16x8*)&lA[(l4 * 128 + wm + i * 16 + l15) * 8];
        #pragma unroll
        for (int j = 0; j < 4; ++j)
            bfr[j] = *(const bf16x8*)&lB[(l4 * 128 + wn + j * 16 + l15) * 8];
        #pragma unroll
        for (int i = 0; i < 4; ++i)
            #pragma unroll
            for (int j = 0; j < 4; ++j)
                acc[i][j] = __builtin_amdgcn_mfma_f32_16x16x32_bf16(
                    af[i], bfr[j], acc[i][j], 0, 0, 0);
        __syncthreads();
    }
    #pragma unroll
    for (int i = 0; i < 4; ++i) {
        #pragma unroll
        for (int r = 0; r < 4; ++r) {
            const int row = bm + wm + i * 16 + l4 * 4 + r;
            #pragma unroll
            for (int j = 0; j < 4; ++j) {
                const int col = bn + wn + j * 16 + l15;
                if (col < N) {
                    float v = acc[i][j][r];
                    if (MODE == 1) v += bias[col];
                    if (MODE == 2) v = softplusf_(v + bias[col]);
                    if (MODE == 3) v += C[(size_t)row * ldc + col];
                    C[(size_t)row * ldc + col] = v;
                }
            }
        }
    }
}

// ---------------------------------------------------------------------------
template<int DUAL>
__global__ __launch_bounds__(256) void conv_silu_k(const float* __restrict__ xz,
                                                   const float* __restrict__ cw,
                                                   const float* __restrict__ cb,
                                                   float* __restrict__ xc,
                                                   short* __restrict__ xcb) {
    int idx = blockIdx.x * 256 + threadIdx.x;
    if (idx >= NTOK * D_INNER) return;
    int d = idx % D_INNER;
    int m = idx / D_INNER;
    int l = m % SEQ;
    float acc = cb[d];
    #pragma unroll
    for (int j = 0; j < D_CONV; ++j) {
        int ll = l - (D_CONV - 1) + j;
        if (ll >= 0)
            acc = fmaf(cw[d * D_CONV + j],
                       xz[(size_t)(m - (D_CONV - 1) + j) * XZ_DIM + d], acc);
    }
    float v = acc * sigmoidf_(acc);
    xc[(size_t)m * D_INNER + d] = v;
    if (DUAL) xcb[(size_t)m * D_INNER + d] = f2bf(v);
}

// ---------------------------------------------------------------------------
// Coalesced chunked selective scan. BF=1: dt/xc/z inputs bf16, y out bf16.
#define SCAN_DW 16
#define SCAN_NC 32
#define SCAN_CL (SEQ / SCAN_NC)   // 16
template<int BF>
__global__ __launch_bounds__(512) void scan3_k(const float* __restrict__ proj,
                                               const void* __restrict__ dtp,
                                               const void* __restrict__ xcp,
                                               const void* __restrict__ zp,
                                               int zld,
                                               const float* __restrict__ A_log,
                                               const float* __restrict__ Dvec,
                                               void* __restrict__ yout) {
    __shared__ float lp[D_STATE][SCAN_NC][SCAN_DW];
    __shared__ float ls[D_STATE][SCAN_NC][SCAN_DW];
    const int nblk_d = D_INNER / SCAN_DW;        // 96
    const int b  = blockIdx.x / nblk_d;
    const int d0 = (blockIdx.x % nblk_d) * SCAN_DW;
    const int t  = threadIdx.x;
    const int dl = t & (SCAN_DW - 1);
    const int c  = t >> 4;
    const int d  = d0 + dl;

    float A[D_STATE];
    #pragma unroll
    for (int s = 0; s < D_STATE; s += 4) {
        float4 a4 = *(const float4*)&A_log[(size_t)d * D_STATE + s];
        A[s+0] = -__expf(a4.x); A[s+1] = -__expf(a4.y);
        A[s+2] = -__expf(a4.z); A[s+3] = -__expf(a4.w);
    }
    const int m0 = b * SEQ + c * SCAN_CL;

    float P[D_STATE], S[D_STATE];
    #pragma unroll
    for (int s = 0; s < D_STATE; ++s) { P[s] = 1.f; S[s] = 0.f; }
    for (int i = 0; i < SCAN_CL; ++i) {
        const int m = m0 + i;
        float dtv, xcv;
        if (BF) {
            dtv = bf2f(((const short*)dtp)[(size_t)m * D_INNER + d]);
            xcv = bf2f(((const short*)xcp)[(size_t)m * D_INNER + d]);
        } else {
            dtv = ((const float*)dtp)[(size_t)m * D_INNER + d];
            xcv = ((const float*)xcp)[(size_t)m * D_INNER + d];
        }
        float dx = dtv * xcv;
        const float* pB = proj + (size_t)m * PROJ_DIM + DT_RANK;
        float Bv[D_STATE];
        #pragma unroll
        for (int s = 0; s < D_STATE; s += 4)
            *(float4*)&Bv[s] = *(const float4*)(pB + s);
        #pragma unroll
        for (int s = 0; s < D_STATE; ++s) {
            float da = __expf(dtv * A[s]);
            S[s] = fmaf(da, S[s], dx * Bv[s]);
            P[s] *= da;
        }
    }
    #pragma unroll
    for (int s = 0; s < D_STATE; ++s) { lp[s][c][dl] = P[s]; ls[s][c][dl] = S[s]; }
    __syncthreads();

    float st[D_STATE];
    #pragma unroll
    for (int s = 0; s < D_STATE; ++s) st[s] = 0.f;
    for (int j = 0; j < c; ++j) {
        #pragma unroll
        for (int s = 0; s < D_STATE; ++s)
            st[s] = fmaf(lp[s][j][dl], st[s], ls[s][j][dl]);
    }

    const float Dvv = Dvec[d];
    for (int i = 0; i < SCAN_CL; ++i) {
        const int m = m0 + i;
        float dtv, xcv, zv;
        if (BF) {
            dtv = bf2f(((const short*)dtp)[(size_t)m * D_INNER + d]);
            xcv = bf2f(((const short*)xcp)[(size_t)m * D_INNER + d]);
            zv  = bf2f(((const short*)zp)[(size_t)m * zld + d]);
        } else {
            dtv = ((const float*)dtp)[(size_t)m * D_INNER + d];
            xcv = ((const float*)xcp)[(size_t)m * D_INNER + d];
            zv  = ((const float*)zp)[(size_t)m * zld + d];
        }
        float dx = dtv * xcv;
        const float* pB = proj + (size_t)m * PROJ_DIM + DT_RANK;
        float Bv[D_STATE], Cv[D_STATE];
        #pragma unroll
        for (int s = 0; s < D_STATE; s += 4) {
            *(float4*)&Bv[s] = *(const float4*)(pB + s);
            *(float4*)&Cv[s] = *(const float4*)(pB + D_STATE + s);
        }
        float acc = Dvv * xcv;
        #pragma unroll
        for (int s = 0; s < D_STATE; ++s) {
            float da = __expf(dtv * A[s]);
            st[s] = fmaf(da, st[s], dx * Bv[s]);
            acc = fmaf(st[s], Cv[s], acc);
        }
        float yv = acc * (zv * sigmoidf_(zv));
        if (BF) ((short*)yout)[(size_t)m * D_INNER + d] = f2bf(yv);
        else    ((float*)yout)[(size_t)m * D_INNER + d] = yv;
    }
}

// ---------------------------------------------------------------------------
extern "C" void kernel_launch(void* const* d_in, const int* in_sizes, int n_in,
                              void* d_out, int out_size, void* d_ws, size_t ws_size,
                              hipStream_t stream) {
    const float* x           = (const float*)d_in[0];
    const float* W_et        = (const float*)d_in[1];
    const float* b_et        = (const float*)d_in[2];
    const float* in_proj_w   = (const float*)d_in[3];
    const float* conv_w      = (const float*)d_in[4];
    const float* conv_b      = (const float*)d_in[5];
    const float* x_proj_w    = (const float*)d_in[6];
    const float* dt_proj_w   = (const float*)d_in[7];
    const float* dt_proj_b   = (const float*)d_in[8];
    const float* A_log       = (const float*)d_in[9];
    const float* Dv          = (const float*)d_in[10];
    const float* out_proj_w  = (const float*)d_in[11];
    const float* norm_w      = (const float*)d_in[12];
    const float* final_norm_w= (const float*)d_in[13];
    const float* embed       = (const float*)d_in[14];
    float* out = (float*)d_out;
    float* ws  = (float*)d_ws;

    // ---- tier-A layout (R11) ----
    float* h       = ws;                                    // [NTOK][768]
    float* proj    = h + (size_t)NTOK * D_MODEL;            // [NTOK][80]
    float* scratch = proj + (size_t)NTOK * PROJ_DIM;        // partials region
    short* scratch_bf = (short*)scratch;
    short* xt_bf   = (short*)(scratch + (size_t)IN_SPLIT * NTOK * XZ_DIM);
    short* hn_bf   = xt_bf   + (size_t)NTOK * ENC_DIM;
    short* xc_bf   = hn_bf   + (size_t)NTOK * D_MODEL;
    short* z_bf    = xc_bf   + (size_t)NTOK * D_INNER;
    short* dt_bf   = z_bf    + (size_t)NTOK * D_INNER;
    short* proj_bf = dt_bf   + (size_t)NTOK * D_INNER;
    short* yb_bf   = proj_bf + (size_t)NTOK * PROJ_DIM;
    short* wet_bf  = yb_bf   + (size_t)NTOK * D_INNER;
    short* inw_bf  = wet_bf  + (size_t)D_MODEL * ENC_DIM;
    short* xw_bf   = inw_bf  + (size_t)N_LAYERS * XZ_DIM * D_MODEL;
    short* dtw_bf  = xw_bf   + (size_t)N_LAYERS * PROJ_DIM * D_INNER;
    short* ow_bf   = dtw_bf  + (size_t)N_LAYERS * D_INNER * DTW_PAD;
    short* emb_bf  = ow_bf   + (size_t)N_LAYERS * D_MODEL * D_INNER;
    short* end_bf  = emb_bf  + (size_t)VOCAB * D_MODEL;
    size_t needA = (size_t)((char*)end_bf - (char*)d_ws);
    bool tierA = ws_size >= needA;

    dim3 blk(256);
    const int scan_blocks = BATCH * (D_INNER / SCAN_DW);   // 192

    if (tierA) {
        auto cvt = [&](const float* s, short* d, size_t n) {
            int nb = (int)((n / 4 + 255) / 256); if (nb > 2048) nb = 2048;
            cvt_k<<<nb, blk, 0, stream>>>(s, d, (int)n);
        };
        cvt(W_et, wet_bf, (size_t)D_MODEL * ENC_DIM);
        cvt(in_proj_w, inw_bf, (size_t)N_LAYERS * XZ_DIM * D_MODEL);
        cvt(x_proj_w, xw_bf, (size_t)N_LAYERS * PROJ_DIM * D_INNER);
        cvt(out_proj_w, ow_bf, (size_t)N_LAYERS * D_MODEL * D_INNER);
        cvt(embed, emb_bf, (size_t)VOCAB * D_MODEL);
        pad_dtw_k<<<(N_LAYERS * D_INNER * DTW_PAD + 255) / 256, blk, 0, stream>>>(
            dt_proj_w, dtw_bf);

        transpose_x_bf_k<<<(SEQ * BATCH * ENC_DIM + 255) / 256, blk, 0, stream>>>(x, xt_bf);
        gemm_p2<1, 64, 2><<<dim3(NTOK / 64, D_MODEL / 128), blk, 0, stream>>>(
            xt_bf, wet_bf, b_et, h, nullptr,
            NTOK, D_MODEL, ENC_DIM, ENC_DIM, ENC_DIM, D_MODEL, 0);
        rmsnorm_bf_k<<<NTOK, blk, 0, stream>>>(h, norm_w, hn_bf);

        for (int L = 0; L < N_LAYERS; ++L) {
            const short* in_w = inw_bf + (size_t)L * XZ_DIM * D_MODEL;
            const float* cw   = conv_w + (size_t)L * D_INNER * D_CONV;
            const float* cb   = conv_b + (size_t)L * D_INNER;
            const short* xw   = xw_bf  + (size_t)L * PROJ_DIM * D_INNER;
            const short* dtw  = dtw_bf + (size_t)L * D_INNER * DTW_PAD;
            const float* dtbp = dt_proj_b + (size_t)L * D_INNER;
            const float* Al   = A_log  + (size_t)L * D_INNER * D_STATE;
            const float* Dl   = Dv     + (size_t)L * D_INNER;
            const short* ow   = ow_bf  + (size_t)L * D_MODEL * D_INNER;
            const float* nw_next = (L == N_LAYERS - 1) ? final_norm_w
                                 : norm_w + (size_t)(L + 1) * D_MODEL;

            gemm_p2<7, 64, 3><<<dim3(NTOK / 64, XZ_DIM / 128, IN_SPLIT), blk, 0, stream>>>(
                hn_bf, in_w, nullptr, nullptr, scratch_bf,
                NTOK, XZ_DIM, D_MODEL / IN_SPLIT, D_MODEL, D_MODEL, 0, XZ_DIM);
            reduce_conv_k<<<(NTOK * XZ_DIM / 8 + 255) / 256, blk, 0, stream>>>(
                scratch_bf, cw, cb, xc_bf, z_bf);
            gemm_p2<7, 64, 3><<<dim3(NTOK / 64, 1, XP_SPLIT), blk, 0, stream>>>(
                xc_bf, xw, nullptr, nullptr, scratch_bf,
                NTOK, PROJ_DIM, D_INNER / XP_SPLIT, D_INNER, D_INNER, 0, PROJ_DIM);
            reduce_xp_k<<<(NTOK * PROJ_DIM / 4 + 255) / 256, blk, 0, stream>>>(
                scratch_bf, proj, proj_bf);
            gemm_p2<6, 64, 2><<<dim3(NTOK / 64, D_INNER / 128), blk, 0, stream>>>(
                proj_bf, dtw, dtbp, h /*dummy*/, dt_bf,
                NTOK, D_INNER, DTW_PAD, PROJ_DIM, DTW_PAD, D_INNER, D_INNER);
            scan3_k<1><<<scan_blocks, dim3(512), 0, stream>>>(
                proj, dt_bf, xc_bf, z_bf, D_INNER, Al, Dl, yb_bf);
            gemm_p2<7, 64, 3><<<dim3(NTOK / 64, D_MODEL / 128, OP_SPLIT), blk, 0, stream>>>(
                yb_bf, ow, nullptr, nullptr, scratch_bf,
                NTOK, D_MODEL, D_INNER / OP_SPLIT, D_INNER, D_INNER, 0, D_MODEL);
            reduce_rms_k<<<NTOK, blk, 0, stream>>>(scratch_bf, h, nw_next, hn_bf);
        }

        gemm_p2<0, 128, 2><<<dim3(NTOK / 128, (VOCAB + 127) / 128), blk, 0, stream>>>(
            hn_bf, emb_bf, nullptr, out, nullptr,
            NTOK, VOCAB, D_MODEL, D_MODEL, D_MODEL, VOCAB, 0);
    } else {
        // ---- tier B fallback (fp32 intermediates) ----
        float* hB   = ws;
        float* hnB  = hB   + (size_t)NTOK * D_MODEL;
        float* xzB  = hnB  + (size_t)NTOK * D_MODEL;
        float* xcB  = xzB  + (size_t)NTOK * XZ_DIM;
        float* projB= xcB  + (size_t)NTOK * D_INNER;
        float* dtB  = projB+ (size_t)NTOK * PROJ_DIM;
        float* ybB  = dtB  + (size_t)NTOK * D_INNER;

        transpose_x_k<<<(SEQ * BATCH * ENC_DIM + 255) / 256, blk, 0, stream>>>(x, ybB);
        gemm_bf16<1><<<dim3(NTOK / 128, D_MODEL / 128), blk, 0, stream>>>(
            ybB, W_et, b_et, hB, NTOK, D_MODEL, ENC_DIM, ENC_DIM, ENC_DIM, D_MODEL);
        for (int L = 0; L < N_LAYERS; ++L) {
            const float* in_w = in_proj_w  + (size_t)L * XZ_DIM * D_MODEL;
            const float* cw   = conv_w     + (size_t)L * D_INNER * D_CONV;
            const float* cb   = conv_b     + (size_t)L * D_INNER;
            const float* xw   = x_proj_w   + (size_t)L * PROJ_DIM * D_INNER;
            const float* dtw  = dt_proj_w  + (size_t)L * D_INNER * DT_RANK;
            const float* dtbp = dt_proj_b  + (size_t)L * D_INNER;
            const float* Al   = A_log      + (size_t)L * D_INNER * D_STATE;
            const float* Dl   = Dv         + (size_t)L * D_INNER;
            const float* ow   = out_proj_w + (size_t)L * D_MODEL * D_INNER;
            const float* nw   = norm_w     + (size_t)L * D_MODEL;
            rmsnorm_k<<<NTOK, blk, 0, stream>>>(hB, nw, hnB);
            gemm_bf16<0><<<dim3(NTOK / 128, XZ_DIM / 128), blk, 0, stream>>>(
                hnB, in_w, nullptr, xzB, NTOK, XZ_DIM, D_MODEL, D_MODEL, D_MODEL, XZ_DIM);
            conv_silu_k<0><<<(NTOK * D_INNER + 255) / 256, blk, 0, stream>>>(
                xzB, cw, cb, xcB, nullptr);
            gemm_bf16<0><<<dim3(NTOK / 128, 1), blk, 0, stream>>>(
                xcB, xw, nullptr, projB, NTOK, PROJ_DIM, D_INNER, D_INNER, D_INNER, PROJ_DIM);
            gemm_bf16<2><<<dim3(NTOK / 128, D_INNER / 128), blk, 0, stream>>>(
                projB, dtw, dtbp, dtB, NTOK, D_INNER, DT_RANK, PROJ_DIM, DT_RANK, D_INNER);
            scan3_k<0><<<scan_blocks, dim3(512), 0, stream>>>(
                projB, dtB, xcB, xzB + D_INNER, XZ_DIM, Al, Dl, ybB);
            gemm_bf16<3><<<dim3(NTOK / 128, D_MODEL / 128), blk, 0, stream>>>(
                ybB, ow, nullptr, hB, NTOK, D_MODEL, D_INNER, D_INNER, D_INNER, D_MODEL);
        }
        rmsnorm_k<<<NTOK, blk, 0, stream>>>(hB, final_norm_w, hnB);
        gemm_bf16<0><<<dim3(NTOK / 128, (VOCAB + 127) / 128), blk, 0, stream>>>(
            hnB, embed, nullptr, out, NTOK, VOCAB, D_MODEL, D_MODEL, D_MODEL, VOCAB);
    }
}